// Round 6
// baseline (3688.271 us; speedup 1.0000x reference)
//
#include <hip/hip_runtime.h>
#include <math.h>
#include <stdint.h>

#define NN 50000
#define FIN 128
#define HD 64
#define CD 32
#define EE 1600000
#define CSTV 1e-5f
#define NB 49  // ceil(NN/1024)

typedef unsigned short u16;
typedef unsigned int u32;
typedef unsigned int uv2 __attribute__((ext_vector_type(2)));
typedef unsigned int uv4 __attribute__((ext_vector_type(4)));

static __device__ __forceinline__ float b2f(u16 u){
  union { float f; u32 i; } v; v.i = ((u32)u) << 16; return v.f;
}
static __device__ __forceinline__ u16 f2b(float f){
  union { float f; u32 u; } v; v.f = f;
  u32 u = v.u;
  u32 r = (u + 0x7fffu + ((u >> 16) & 1u)) >> 16;
  return (u16)r;
}
static __device__ __forceinline__ u32 pack2(float a, float b){
  return (u32)f2b(a) | ((u32)f2b(b) << 16);
}
static __device__ __forceinline__ float ldin(const void* p, size_t i, int isf){
  return isf ? ((const float*)p)[i] : b2f(((const u16*)p)[i]);
}

template<int C>
static __device__ __forceinline__ void loadB(const u16* __restrict__ p, float* f){
  if constexpr (C == 16){
    uint4 g0 = ((const uint4*)p)[0];
    uint4 g1 = ((const uint4*)p)[1];
    f[0]=b2f((u16)(g0.x&0xffff)); f[1]=b2f((u16)(g0.x>>16));
    f[2]=b2f((u16)(g0.y&0xffff)); f[3]=b2f((u16)(g0.y>>16));
    f[4]=b2f((u16)(g0.z&0xffff)); f[5]=b2f((u16)(g0.z>>16));
    f[6]=b2f((u16)(g0.w&0xffff)); f[7]=b2f((u16)(g0.w>>16));
    f[8]=b2f((u16)(g1.x&0xffff)); f[9]=b2f((u16)(g1.x>>16));
    f[10]=b2f((u16)(g1.y&0xffff)); f[11]=b2f((u16)(g1.y>>16));
    f[12]=b2f((u16)(g1.z&0xffff)); f[13]=b2f((u16)(g1.z>>16));
    f[14]=b2f((u16)(g1.w&0xffff)); f[15]=b2f((u16)(g1.w>>16));
  } else if constexpr (C == 8){
    uint4 g = *(const uint4*)p;
    f[0]=b2f((u16)(g.x&0xffff)); f[1]=b2f((u16)(g.x>>16));
    f[2]=b2f((u16)(g.y&0xffff)); f[3]=b2f((u16)(g.y>>16));
    f[4]=b2f((u16)(g.z&0xffff)); f[5]=b2f((u16)(g.z>>16));
    f[6]=b2f((u16)(g.w&0xffff)); f[7]=b2f((u16)(g.w>>16));
  } else if constexpr (C == 4){
    uint2 g = *(const uint2*)p;
    f[0]=b2f((u16)(g.x&0xffff)); f[1]=b2f((u16)(g.x>>16));
    f[2]=b2f((u16)(g.y&0xffff)); f[3]=b2f((u16)(g.y>>16));
  } else {
    u32 g = *(const u32*)p;
    f[0]=b2f((u16)(g&0xffff)); f[1]=b2f((u16)(g>>16));
  }
}
template<int C>
static __device__ __forceinline__ void storeNT(u16* __restrict__ p, const float* f){
  if constexpr (C == 16){
    uv4 g0, g1;
    g0.x=pack2(f[0],f[1]); g0.y=pack2(f[2],f[3]); g0.z=pack2(f[4],f[5]); g0.w=pack2(f[6],f[7]);
    g1.x=pack2(f[8],f[9]); g1.y=pack2(f[10],f[11]); g1.z=pack2(f[12],f[13]); g1.w=pack2(f[14],f[15]);
    __builtin_nontemporal_store(g0, (uv4*)p);
    __builtin_nontemporal_store(g1, (uv4*)p + 1);
  } else if constexpr (C == 8){
    uv4 g; g.x=pack2(f[0],f[1]); g.y=pack2(f[2],f[3]); g.z=pack2(f[4],f[5]); g.w=pack2(f[6],f[7]);
    __builtin_nontemporal_store(g, (uv4*)p);
  } else if constexpr (C == 4){
    uv2 g; g.x=pack2(f[0],f[1]); g.y=pack2(f[2],f[3]);
    __builtin_nontemporal_store(g, (uv2*)p);
  } else {
    __builtin_nontemporal_store(pack2(f[0],f[1]), (u32*)p);
  }
}

// ---------------- dtype detect ----------------
__global__ void k_detect(const u16* __restrict__ w, int* __restrict__ flag){
  __shared__ int bad;
  if (threadIdx.x == 0) bad = 0;
  __syncthreads();
  for (int i = threadIdx.x; i < 2048; i += 256){
    float v = b2f(w[i]);
    if (!(fabsf(v) <= 1.0f)) bad = 1;
  }
  __syncthreads();
  if (threadIdx.x == 0) flag[0] = bad;  // 1 = fp32 inputs, 0 = bf16
}

// ---------------- CSR build ----------------

__global__ void k_zero(int* cnt, float* teleM, float* teleK){
  int i = blockIdx.x * 256 + threadIdx.x;
  if (i < NN) cnt[i] = 0;
  if (i < HD * CD) teleM[i] = 0.f;
  if (i < HD) teleK[i] = 0.f;
}

__global__ void k_hist(const int* __restrict__ colp, int* __restrict__ cnt){
  int e = blockIdx.x * 256 + threadIdx.x;
  if (e < EE) atomicAdd(&cnt[colp[e]], 1);
}

__global__ __launch_bounds__(1024) void k_scanA(const int* __restrict__ cnt,
                                                int* __restrict__ loc, int* __restrict__ bsum){
  __shared__ int wsum[16];
  int t = threadIdx.x; int i = blockIdx.x * 1024 + t;
  int v = (i < NN) ? cnt[i] : 0;
  int x = v;
  int lane = t & 63, wid = t >> 6;
  #pragma unroll
  for (int d = 1; d < 64; d <<= 1){ int n = __shfl_up(x, d, 64); if (lane >= d) x += n; }
  if (lane == 63) wsum[wid] = x;
  __syncthreads();
  if (t < 16){
    int y = wsum[t];
    #pragma unroll
    for (int d = 1; d < 16; d <<= 1){ int n = __shfl_up(y, d, 16); if (t >= d) y += n; }
    wsum[t] = y;
  }
  __syncthreads();
  if (wid > 0) x += wsum[wid - 1];
  if (i < NN) loc[i] = x;
  if (t == 1023) bsum[blockIdx.x] = x;
}

__global__ __launch_bounds__(64) void k_scanB(const int* __restrict__ bsum,
                                              int* __restrict__ boff, int* __restrict__ ptrNN){
  int t = threadIdx.x;
  int v = (t < NB) ? bsum[t] : 0;
  int x = v;
  #pragma unroll
  for (int d = 1; d < 64; d <<= 1){ int n = __shfl_up(x, d, 64); if (t >= d) x += n; }
  if (t < NB) boff[t] = x - v;
  if (t == 63) ptrNN[0] = x;
}

__global__ __launch_bounds__(1024) void k_scanC(const int* __restrict__ cnt, const int* __restrict__ loc,
                                                const int* __restrict__ boff, int* __restrict__ ptr,
                                                int* __restrict__ fill, float* __restrict__ dinv){
  int i = blockIdx.x * 1024 + threadIdx.x;
  if (i < NN){
    int c = cnt[i];
    int p = boff[blockIdx.x] + loc[i] - c;
    ptr[i] = p; fill[i] = p;
    dinv[i] = (c > 0) ? 1.f / (float)c : 0.f;
  }
}

__global__ void k_scatter(const int* __restrict__ rowp, const int* __restrict__ colp,
                          const float* __restrict__ dinv, int* __restrict__ fill,
                          int2* __restrict__ ew){
  int e = blockIdx.x * 256 + threadIdx.x;
  if (e < EE){
    int c = colp[e];
    int p = atomicAdd(&fill[c], 1);
    int r = rowp[e];
    int2 v; v.x = r; v.y = __float_as_int(dinv[r]);
    ew[p] = v;
  }
}

// ---------------- featurizer ----------------

__global__ __launch_bounds__(256) void k_x(const void* __restrict__ feat, const void* __restrict__ Win,
                                           const void* __restrict__ bin, const int* __restrict__ fl,
                                           float* __restrict__ x){
  int isf = fl[0];
  __shared__ float Ws[FIN * HD];
  __shared__ float fs[4 * FIN];
  __shared__ float bs[HD];
  int t = threadIdx.x;
  for (int idx = t; idx < FIN * HD; idx += 256) Ws[idx] = ldin(Win, idx, isf);
  if (t < HD) bs[t] = ldin(bin, t, isf);
  int n0 = blockIdx.x * 4;
  for (int idx = t; idx < 4 * FIN; idx += 256){
    int nl = idx >> 7, k = idx & 127; int n = n0 + nl;
    fs[idx] = (n < NN) ? ldin(feat, (size_t)n * FIN + k, isf) : 0.f;
  }
  __syncthreads();
  int nl = t >> 6, o = t & 63; int n = n0 + nl;
  if (n < NN){
    float acc = bs[o];
    #pragma unroll 8
    for (int k = 0; k < FIN; ++k) acc += fs[nl * FIN + k] * Ws[k * HD + o];
    x[(size_t)n * HD + o] = fmaxf(acc, 0.f);
  }
}

__global__ __launch_bounds__(256) void k_qkv(const float* __restrict__ x,
    const void* __restrict__ WQ, const void* __restrict__ bQ,
    const void* __restrict__ WK, const void* __restrict__ bK,
    const void* __restrict__ WV, const void* __restrict__ bV,
    const void* __restrict__ hopwise, const int* __restrict__ fl,
    float* __restrict__ Q, u16* __restrict__ Kf0b, u16* __restrict__ Vb,
    float* __restrict__ hid){
  int isf = fl[0];
  __shared__ float WQs[HD * HD], WKs[HD * HD], WVs[HD * CD];
  __shared__ float bqs[HD], bks[HD], bvs[CD];
  __shared__ float xs[4 * HD];
  int t = threadIdx.x;
  for (int idx = t; idx < HD * HD; idx += 256){ WQs[idx] = ldin(WQ, idx, isf); WKs[idx] = ldin(WK, idx, isf); }
  for (int idx = t; idx < HD * CD; idx += 256) WVs[idx] = ldin(WV, idx, isf);
  if (t < HD){ bqs[t] = ldin(bQ, t, isf); bks[t] = ldin(bK, t, isf); }
  if (t < CD) bvs[t] = ldin(bV, t, isf);
  int n0 = blockIdx.x * 4;
  for (int idx = t; idx < 4 * HD; idx += 256){
    int nl = idx >> 6; int n = n0 + nl;
    xs[idx] = (n < NN) ? x[(size_t)n * HD + (idx & 63)] : 0.f;
  }
  __syncthreads();
  int nl = t >> 6, o = t & 63; int n = n0 + nl;
  float hw0 = ldin(hopwise, 0, isf);
  float q = bqs[o], kf = bks[o];
  #pragma unroll 8
  for (int k = 0; k < HD; ++k){
    float xv = xs[nl * HD + k];
    q  += xv * WQs[k * HD + o];
    kf += xv * WKs[k * HD + o];
  }
  q  = (q  > 0.f) ? 1.f + q  : expf(q);
  kf = (kf > 0.f) ? 1.f + kf : expf(kf);
  if (n < NN){ Q[(size_t)n * HD + o] = q; Kf0b[(size_t)n * HD + o] = f2b(kf); }
  if (o < CD && n < NN){
    float v = bvs[o];
    #pragma unroll 8
    for (int k = 0; k < HD; ++k) v += xs[nl * HD + k] * WVs[k * CD + o];
    Vb[(size_t)n * CD + o] = f2b(v);
    hid[(size_t)n * CD + o] = hw0 * v;
  }
}

// ---------------- teleport sums ----------------

__global__ __launch_bounds__(256) void k_tele(const u16* __restrict__ Kf0b, const u16* __restrict__ Vb,
                                              float* __restrict__ teleM, float* __restrict__ teleK){
  __shared__ float accM[HD * CD];
  __shared__ float accKs[HD];
  __shared__ float KfL[HD];
  __shared__ float VL[CD];
  int t = threadIdx.x;
  for (int idx = t; idx < HD * CD; idx += 256) accM[idx] = 0.f;
  if (t < HD) accKs[t] = 0.f;
  __syncthreads();
  for (int n = blockIdx.x; n < NN; n += gridDim.x){
    if (t < HD) KfL[t] = b2f(Kf0b[(size_t)n * HD + t]);
    else if (t < HD + CD) VL[t - HD] = b2f(Vb[(size_t)n * CD + (t - HD)]);
    __syncthreads();
    for (int idx = t; idx < HD * CD; idx += 256){
      int h = idx >> 5, c = idx & 31;
      accM[idx] += KfL[h] * VL[c];
    }
    if (t < HD) accKs[t] += KfL[t];
    __syncthreads();
  }
  for (int idx = t; idx < HD * CD; idx += 256) atomicAdd(&teleM[idx], accM[idx]);
  if (t < HD) atomicAdd(&teleK[t], accKs[t]);
}

// ---------------- hop: gather-propagate + fused readout (+optional Kf prop) ----------------
// 128-thread block = 2 waves = 2 target nodes (one per wave; occupancy 2x vs 64-thr).
// Lane t owns row h=t, columns [c0, c0+C).
// FIRST: M_in implicit rank-1 Kf0 (x) V. FUSEK: also propagate Kf + compute invC.

template<int C, bool FIRST, bool FUSEK, bool LAST>
__global__ __launch_bounds__(128)
void k_hop(const u16* __restrict__ Min, const u16* __restrict__ Kf0b, const u16* __restrict__ Vb,
           const u16* __restrict__ KfIn, u16* __restrict__ KfOut,
           const float* __restrict__ Qb, const int2* __restrict__ ew, const int* __restrict__ ptr,
           float* __restrict__ invC, const void* __restrict__ hopw, const int* __restrict__ fl,
           int hopidx, u16* __restrict__ Mout, float* __restrict__ hid, int c0){
  int wv = threadIdx.x >> 6;
  int t = threadIdx.x & 63;          // lane within wave = h row
  int i = blockIdx.x * 2 + wv;       // target node (NN even; grid*2 == NN)
  int e0 = __builtin_amdgcn_readfirstlane(ptr[i]);
  int e1 = __builtin_amdgcn_readfirstlane(ptr[i + 1]);
  float a[C];
  #pragma unroll
  for (int j = 0; j < C; ++j) a[j] = 0.f;
  float accK = 0.f;
  int e = e0;
  if constexpr (FIRST){
    for (; e + 4 <= e1; e += 4){
      int2 d0 = ew[e], d1 = ew[e+1], d2 = ew[e+2], d3 = ew[e+3];
      float s0 = __int_as_float(d0.y) * b2f(Kf0b[(size_t)d0.x * HD + t]);
      float s1 = __int_as_float(d1.y) * b2f(Kf0b[(size_t)d1.x * HD + t]);
      float s2 = __int_as_float(d2.y) * b2f(Kf0b[(size_t)d2.x * HD + t]);
      float s3 = __int_as_float(d3.y) * b2f(Kf0b[(size_t)d3.x * HD + t]);
      float v0[C], v1[C], v2[C], v3[C];
      loadB<C>(Vb + (size_t)d0.x * CD + c0, v0);
      loadB<C>(Vb + (size_t)d1.x * CD + c0, v1);
      loadB<C>(Vb + (size_t)d2.x * CD + c0, v2);
      loadB<C>(Vb + (size_t)d3.x * CD + c0, v3);
      #pragma unroll
      for (int j = 0; j < C; ++j) a[j] += s0 * v0[j] + s1 * v1[j] + s2 * v2[j] + s3 * v3[j];
      if constexpr (FUSEK) accK += s0 + s1 + s2 + s3;
    }
    for (; e < e1; ++e){
      int2 d0 = ew[e];
      float s0 = __int_as_float(d0.y) * b2f(Kf0b[(size_t)d0.x * HD + t]);
      float v0[C];
      loadB<C>(Vb + (size_t)d0.x * CD + c0, v0);
      #pragma unroll
      for (int j = 0; j < C; ++j) a[j] += s0 * v0[j];
      if constexpr (FUSEK) accK += s0;
    }
  } else {
    for (; e + 4 <= e1; e += 4){
      int2 d0 = ew[e], d1 = ew[e+1], d2 = ew[e+2], d3 = ew[e+3];
      float w0 = __int_as_float(d0.y), w1 = __int_as_float(d1.y);
      float w2 = __int_as_float(d2.y), w3 = __int_as_float(d3.y);
      float m0[C], m1[C], m2[C], m3[C];
      loadB<C>(Min + (size_t)d0.x * (HD * C) + t * C, m0);
      loadB<C>(Min + (size_t)d1.x * (HD * C) + t * C, m1);
      loadB<C>(Min + (size_t)d2.x * (HD * C) + t * C, m2);
      loadB<C>(Min + (size_t)d3.x * (HD * C) + t * C, m3);
      if constexpr (FUSEK){
        accK += w0 * b2f(KfIn[(size_t)d0.x * HD + t]) + w1 * b2f(KfIn[(size_t)d1.x * HD + t])
              + w2 * b2f(KfIn[(size_t)d2.x * HD + t]) + w3 * b2f(KfIn[(size_t)d3.x * HD + t]);
      }
      #pragma unroll
      for (int j = 0; j < C; ++j) a[j] += w0 * m0[j] + w1 * m1[j] + w2 * m2[j] + w3 * m3[j];
    }
    for (; e < e1; ++e){
      int2 d0 = ew[e];
      float w0 = __int_as_float(d0.y);
      float m0[C];
      loadB<C>(Min + (size_t)d0.x * (HD * C) + t * C, m0);
      if constexpr (FUSEK) accK += w0 * b2f(KfIn[(size_t)d0.x * HD + t]);
      #pragma unroll
      for (int j = 0; j < C; ++j) a[j] += w0 * m0[j];
    }
  }
  float q = Qb[(size_t)i * HD + t];
  float ic;
  if constexpr (FUSEK){
    if constexpr (!LAST) KfOut[(size_t)i * HD + t] = f2b(accK);
    float ck = q * accK;
    #pragma unroll
    for (int off = 32; off >= 1; off >>= 1) ck += __shfl_down(ck, off, 64);
    ck = 1.f / (ck + CSTV);          // valid on lane 0
    if (t == 0) invC[i] = ck;
    ic = ck;
  } else {
    ic = invC[i];
  }
  float p[C];
  #pragma unroll
  for (int j = 0; j < C; ++j) p[j] = q * a[j];
  #pragma unroll
  for (int off = 32; off >= 1; off >>= 1){
    #pragma unroll
    for (int j = 0; j < C; ++j) p[j] += __shfl_down(p[j], off, 64);
  }
  if (t == 0){
    float coef = ldin(hopw, hopidx, fl[0]) * ic;
    float* hp = hid + (size_t)i * CD + c0;
    #pragma unroll
    for (int j = 0; j < C; ++j) hp[j] += coef * p[j];
  }
  if constexpr (!LAST) storeNT<C>(Mout + (size_t)i * (HD * C) + t * C, a);
}

// ---------------- teleport branch + output ----------------

__global__ __launch_bounds__(256) void k_final(const float* __restrict__ hid, const float* __restrict__ Qb,
    const float* __restrict__ teleM, const float* __restrict__ teleK, const void* __restrict__ tel,
    const int* __restrict__ fl, void* __restrict__ out){
  int isf = fl[0];
  __shared__ float tM[HD * CD];
  __shared__ float tK[HD];
  int t = threadIdx.x;
  for (int idx = t; idx < HD * CD; idx += 256) tM[idx] = teleM[idx];
  if (t < HD) tK[t] = teleK[t];
  __syncthreads();
  int nl = t >> 5, c = t & 31;
  int n = blockIdx.x * 8 + nl;
  if (n < NN){
    const float* q = Qb + (size_t)n * HD;
    float dH = 0.f, dK = 0.f;
    #pragma unroll 8
    for (int h = 0; h < HD; ++h){
      float qv = q[h];
      dH += qv * tM[h * CD + c];
      dK += qv * tK[h];
    }
    float invn = 1.f / (float)NN;
    float tH = (dH * invn) / (dK * invn + CSTV);
    float val = hid[(size_t)n * CD + c] + ldin(tel, 0, isf) * tH;
    if (isf) ((float*)out)[(size_t)n * CD + c] = val;
    else ((u16*)out)[(size_t)n * CD + c] = f2b(val);
  }
}

// ---------------- host-side hop sequencing ----------------

template<int C>
static void launch_chunks(u16* Ma, u16* Mb, const u16* Kf0b, const u16* Vb,
                          u16* KfPa, u16* KfPb, const float* Q, const int2* ew,
                          const int* ptr, float* invC, const void* hop, const int* flag,
                          float* hid, hipStream_t stream){
  int nchunks = CD / C;
  int grid = NN / 2;
  for (int ch = 0; ch < nchunks; ++ch){
    int c0 = ch * C;
    if (ch == 0){
      k_hop<C,true ,true ,false><<<grid,128,0,stream>>>(nullptr, Kf0b, Vb, nullptr, KfPa, Q, ew, ptr, invC+0*NN, hop, flag, 1, Ma, hid, c0);
      k_hop<C,false,true ,false><<<grid,128,0,stream>>>(Ma, Kf0b, Vb, KfPa, KfPb, Q, ew, ptr, invC+1*NN, hop, flag, 2, Mb, hid, c0);
      k_hop<C,false,true ,false><<<grid,128,0,stream>>>(Mb, Kf0b, Vb, KfPb, KfPa, Q, ew, ptr, invC+2*NN, hop, flag, 3, Ma, hid, c0);
      k_hop<C,false,true ,true ><<<grid,128,0,stream>>>(Ma, Kf0b, Vb, KfPa, nullptr, Q, ew, ptr, invC+3*NN, hop, flag, 4, nullptr, hid, c0);
    } else {
      k_hop<C,true ,false,false><<<grid,128,0,stream>>>(nullptr, Kf0b, Vb, nullptr, nullptr, Q, ew, ptr, invC+0*NN, hop, flag, 1, Ma, hid, c0);
      k_hop<C,false,false,false><<<grid,128,0,stream>>>(Ma, Kf0b, Vb, nullptr, nullptr, Q, ew, ptr, invC+1*NN, hop, flag, 2, Mb, hid, c0);
      k_hop<C,false,false,false><<<grid,128,0,stream>>>(Mb, Kf0b, Vb, nullptr, nullptr, Q, ew, ptr, invC+2*NN, hop, flag, 3, Ma, hid, c0);
      k_hop<C,false,false,true ><<<grid,128,0,stream>>>(Ma, Kf0b, Vb, nullptr, nullptr, Q, ew, ptr, invC+3*NN, hop, flag, 4, nullptr, hid, c0);
    }
  }
}

// ---------------- launch ----------------

extern "C" void kernel_launch(void* const* d_in, const int* in_sizes, int n_in,
                              void* d_out, int out_size, void* d_ws, size_t ws_size,
                              hipStream_t stream){
  const void* feat = d_in[0];
  const void* Win  = d_in[1];
  const void* bin  = d_in[2];
  const void* WQ   = d_in[3];
  const void* bQ   = d_in[4];
  const void* WK   = d_in[5];
  const void* bK   = d_in[6];
  const void* WV   = d_in[7];
  const void* bV   = d_in[8];
  const void* hop  = d_in[9];
  const void* tel  = d_in[10];
  const int* ei    = (const int*)d_in[11];
  const int* rowp  = ei;
  const int* colp  = ei + EE;

  char* w = (char*)d_ws;
  size_t off = 0;
  auto pad = [](size_t x){ return (x + 255) & ~((size_t)255); };
  auto alloc = [&](size_t bytes) -> char* {
    char* p = w + off;
    off += pad(bytes);
    return p;
  };
  float* Q    = (float*)alloc((size_t)NN * HD * 4);
  float* hid  = (float*)alloc((size_t)NN * CD * 4);
  float* invC = (float*)alloc((size_t)4 * NN * 4);
  float* dinv = (float*)alloc((size_t)NN * 4);
  int*   cnt  = (int*)alloc((size_t)NN * 4);
  int*   ptr  = (int*)alloc((size_t)(NN + 1) * 4);
  int*   fill = (int*)alloc((size_t)NN * 4);
  int*   bsum = (int*)alloc(64 * 4);
  int*   boff = (int*)alloc(64 * 4);
  int2*  ew   = (int2*)alloc((size_t)EE * 8);
  float* teleM= (float*)alloc((size_t)HD * CD * 4);
  float* teleK= (float*)alloc((size_t)HD * 4);
  int*   flag = (int*)alloc(256);
  u16*   Kf0b = (u16*)alloc((size_t)NN * HD * 2);
  u16*   KfPa = (u16*)alloc((size_t)NN * HD * 2);
  u16*   KfPb = (u16*)alloc((size_t)NN * HD * 2);
  u16*   Vb   = (u16*)alloc((size_t)NN * CD * 2);

  size_t fixed = off;
  auto fits = [&](int C){ return fixed + 2 * pad((size_t)NN * HD * C * 2) <= ws_size; };
  int C = fits(16) ? 16 : (fits(8) ? 8 : (fits(4) ? 4 : 2));
  size_t mbytes = pad((size_t)NN * HD * C * 2);
  char* mreg = alloc(2 * mbytes);
  u16* Ma = (u16*)mreg;
  u16* Mb = (u16*)(mreg + mbytes);
  float* x = (float*)mreg;  // x (12.8 MB) aliases M region (>=12.8 MB in all tiers); dead before hops

  k_detect<<<1, 256, 0, stream>>>((const u16*)Win, flag);
  k_zero<<<(NN + 255) / 256, 256, 0, stream>>>(cnt, teleM, teleK);
  k_hist<<<(EE + 255) / 256, 256, 0, stream>>>(colp, cnt);
  k_scanA<<<NB, 1024, 0, stream>>>(cnt, fill, bsum);
  k_scanB<<<1, 64, 0, stream>>>(bsum, boff, ptr + NN);
  k_scanC<<<NB, 1024, 0, stream>>>(cnt, fill, boff, ptr, fill, dinv);
  k_scatter<<<(EE + 255) / 256, 256, 0, stream>>>(rowp, colp, dinv, fill, ew);
  k_x<<<(NN + 3) / 4, 256, 0, stream>>>(feat, Win, bin, flag, x);
  k_qkv<<<(NN + 3) / 4, 256, 0, stream>>>(x, WQ, bQ, WK, bK, WV, bV, hop, flag, Q, Kf0b, Vb, hid);
  k_tele<<<256, 256, 0, stream>>>(Kf0b, Vb, teleM, teleK);

  if (C == 16)      launch_chunks<16>(Ma, Mb, Kf0b, Vb, KfPa, KfPb, Q, ew, ptr, invC, hop, flag, hid, stream);
  else if (C == 8)  launch_chunks<8 >(Ma, Mb, Kf0b, Vb, KfPa, KfPb, Q, ew, ptr, invC, hop, flag, hid, stream);
  else if (C == 4)  launch_chunks<4 >(Ma, Mb, Kf0b, Vb, KfPa, KfPb, Q, ew, ptr, invC, hop, flag, hid, stream);
  else              launch_chunks<2 >(Ma, Mb, Kf0b, Vb, KfPa, KfPb, Q, ew, ptr, invC, hop, flag, hid, stream);

  k_final<<<(NN + 7) / 8, 256, 0, stream>>>(hid, Q, teleM, teleK, tel, flag, d_out);
}

// Round 7
// 2278.718 us; speedup vs baseline: 1.6186x; 1.6186x over previous
//
#include <hip/hip_runtime.h>
#include <math.h>
#include <stdint.h>

#define NN 50000
#define FIN 128
#define HD 64
#define CD 32
#define EE 1600000
#define CSTV 1e-5f
#define NB 49  // ceil(NN/1024)

typedef unsigned short u16;
typedef unsigned int u32;
typedef unsigned char u8;
typedef unsigned int uv2 __attribute__((ext_vector_type(2)));
typedef unsigned int uv4 __attribute__((ext_vector_type(4)));
typedef float fv2 __attribute__((ext_vector_type(2)));

static __device__ __forceinline__ float b2f(u16 u){
  union { float f; u32 i; } v; v.i = ((u32)u) << 16; return v.f;
}
static __device__ __forceinline__ u16 f2b(float f){
  union { float f; u32 u; } v; v.f = f;
  u32 u = v.u;
  u32 r = (u + 0x7fffu + ((u >> 16) & 1u)) >> 16;
  return (u16)r;
}
static __device__ __forceinline__ float ldin(const void* p, size_t i, int isf){
  return isf ? ((const float*)p)[i] : b2f(((const u16*)p)[i]);
}

// ---- fp8 e4m3 via HW converters (encode/decode matched => self-consistent) ----
static __device__ __forceinline__ void dec8(u32 g, float* f){
  fv2 lo = __builtin_amdgcn_cvt_pk_f32_fp8(g, false);
  fv2 hi = __builtin_amdgcn_cvt_pk_f32_fp8(g, true);
  f[0] = lo.x; f[1] = lo.y; f[2] = hi.x; f[3] = hi.y;
}
static __device__ __forceinline__ u32 enc8(const float* f){
  u32 r = 0;
  r = __builtin_amdgcn_cvt_pk_fp8_f32(f[0], f[1], r, false);
  r = __builtin_amdgcn_cvt_pk_fp8_f32(f[2], f[3], r, true);
  return r;
}
template<int C>
static __device__ __forceinline__ void loadF8(const u8* __restrict__ p, float* f){
  if constexpr (C == 32){
    uint4 g0 = ((const uint4*)p)[0];
    uint4 g1 = ((const uint4*)p)[1];
    dec8(g0.x, f+0);  dec8(g0.y, f+4);  dec8(g0.z, f+8);  dec8(g0.w, f+12);
    dec8(g1.x, f+16); dec8(g1.y, f+20); dec8(g1.z, f+24); dec8(g1.w, f+28);
  } else if constexpr (C == 16){
    uint4 g = *(const uint4*)p;
    dec8(g.x, f+0); dec8(g.y, f+4); dec8(g.z, f+8); dec8(g.w, f+12);
  } else {
    uint2 g = *(const uint2*)p;
    dec8(g.x, f+0); dec8(g.y, f+4);
  }
}
template<int C>
static __device__ __forceinline__ void storeF8NT(u8* __restrict__ p, const float* f){
  if constexpr (C == 32){
    uv4 g0, g1;
    g0.x=enc8(f+0);  g0.y=enc8(f+4);  g0.z=enc8(f+8);  g0.w=enc8(f+12);
    g1.x=enc8(f+16); g1.y=enc8(f+20); g1.z=enc8(f+24); g1.w=enc8(f+28);
    __builtin_nontemporal_store(g0, (uv4*)p);
    __builtin_nontemporal_store(g1, (uv4*)p + 1);
  } else if constexpr (C == 16){
    uv4 g; g.x=enc8(f+0); g.y=enc8(f+4); g.z=enc8(f+8); g.w=enc8(f+12);
    __builtin_nontemporal_store(g, (uv4*)p);
  } else {
    uv2 g; g.x=enc8(f+0); g.y=enc8(f+4);
    __builtin_nontemporal_store(g, (uv2*)p);
  }
}
// bf16 row load (V rows in the rank-1 first hop)
template<int C>
static __device__ __forceinline__ void loadB(const u16* __restrict__ p, float* f){
  if constexpr (C == 32){
    #pragma unroll
    for (int q = 0; q < 4; ++q){
      uint4 g = ((const uint4*)p)[q];
      f[q*8+0]=b2f((u16)(g.x&0xffff)); f[q*8+1]=b2f((u16)(g.x>>16));
      f[q*8+2]=b2f((u16)(g.y&0xffff)); f[q*8+3]=b2f((u16)(g.y>>16));
      f[q*8+4]=b2f((u16)(g.z&0xffff)); f[q*8+5]=b2f((u16)(g.z>>16));
      f[q*8+6]=b2f((u16)(g.w&0xffff)); f[q*8+7]=b2f((u16)(g.w>>16));
    }
  } else if constexpr (C == 16){
    #pragma unroll
    for (int q = 0; q < 2; ++q){
      uint4 g = ((const uint4*)p)[q];
      f[q*8+0]=b2f((u16)(g.x&0xffff)); f[q*8+1]=b2f((u16)(g.x>>16));
      f[q*8+2]=b2f((u16)(g.y&0xffff)); f[q*8+3]=b2f((u16)(g.y>>16));
      f[q*8+4]=b2f((u16)(g.z&0xffff)); f[q*8+5]=b2f((u16)(g.z>>16));
      f[q*8+6]=b2f((u16)(g.w&0xffff)); f[q*8+7]=b2f((u16)(g.w>>16));
    }
  } else {
    uint4 g = *(const uint4*)p;
    f[0]=b2f((u16)(g.x&0xffff)); f[1]=b2f((u16)(g.x>>16));
    f[2]=b2f((u16)(g.y&0xffff)); f[3]=b2f((u16)(g.y>>16));
    f[4]=b2f((u16)(g.z&0xffff)); f[5]=b2f((u16)(g.z>>16));
    f[6]=b2f((u16)(g.w&0xffff)); f[7]=b2f((u16)(g.w>>16));
  }
}

// ---------------- dtype detect ----------------
__global__ void k_detect(const u16* __restrict__ w, int* __restrict__ flag){
  __shared__ int bad;
  if (threadIdx.x == 0) bad = 0;
  __syncthreads();
  for (int i = threadIdx.x; i < 2048; i += 256){
    float v = b2f(w[i]);
    if (!(fabsf(v) <= 1.0f)) bad = 1;
  }
  __syncthreads();
  if (threadIdx.x == 0) flag[0] = bad;  // 1 = fp32 inputs, 0 = bf16
}

// ---------------- CSR build ----------------

__global__ void k_zero(int* cnt, float* teleM, float* teleK){
  int i = blockIdx.x * 256 + threadIdx.x;
  if (i < NN) cnt[i] = 0;
  if (i < HD * CD) teleM[i] = 0.f;
  if (i < HD) teleK[i] = 0.f;
}

__global__ void k_hist(const int* __restrict__ colp, int* __restrict__ cnt){
  int e = blockIdx.x * 256 + threadIdx.x;
  if (e < EE) atomicAdd(&cnt[colp[e]], 1);
}

__global__ __launch_bounds__(1024) void k_scanA(const int* __restrict__ cnt,
                                                int* __restrict__ loc, int* __restrict__ bsum){
  __shared__ int wsum[16];
  int t = threadIdx.x; int i = blockIdx.x * 1024 + t;
  int v = (i < NN) ? cnt[i] : 0;
  int x = v;
  int lane = t & 63, wid = t >> 6;
  #pragma unroll
  for (int d = 1; d < 64; d <<= 1){ int n = __shfl_up(x, d, 64); if (lane >= d) x += n; }
  if (lane == 63) wsum[wid] = x;
  __syncthreads();
  if (t < 16){
    int y = wsum[t];
    #pragma unroll
    for (int d = 1; d < 16; d <<= 1){ int n = __shfl_up(y, d, 16); if (t >= d) y += n; }
    wsum[t] = y;
  }
  __syncthreads();
  if (wid > 0) x += wsum[wid - 1];
  if (i < NN) loc[i] = x;
  if (t == 1023) bsum[blockIdx.x] = x;
}

__global__ __launch_bounds__(64) void k_scanB(const int* __restrict__ bsum,
                                              int* __restrict__ boff, int* __restrict__ ptrNN){
  int t = threadIdx.x;
  int v = (t < NB) ? bsum[t] : 0;
  int x = v;
  #pragma unroll
  for (int d = 1; d < 64; d <<= 1){ int n = __shfl_up(x, d, 64); if (t >= d) x += n; }
  if (t < NB) boff[t] = x - v;
  if (t == 63) ptrNN[0] = x;
}

__global__ __launch_bounds__(1024) void k_scanC(const int* __restrict__ cnt, const int* __restrict__ loc,
                                                const int* __restrict__ boff, int* __restrict__ ptr,
                                                int* __restrict__ fill, float* __restrict__ dinv){
  int i = blockIdx.x * 1024 + threadIdx.x;
  if (i < NN){
    int c = cnt[i];
    int p = boff[blockIdx.x] + loc[i] - c;
    ptr[i] = p; fill[i] = p;
    dinv[i] = (c > 0) ? 1.f / (float)c : 0.f;
  }
}

__global__ void k_scatter(const int* __restrict__ rowp, const int* __restrict__ colp,
                          const float* __restrict__ dinv, int* __restrict__ fill,
                          int2* __restrict__ ew){
  int e = blockIdx.x * 256 + threadIdx.x;
  if (e < EE){
    int c = colp[e];
    int p = atomicAdd(&fill[c], 1);
    int r = rowp[e];
    int2 v; v.x = r; v.y = __float_as_int(dinv[r]);
    ew[p] = v;
  }
}

// ---------------- featurizer ----------------

__global__ __launch_bounds__(256) void k_x(const void* __restrict__ feat, const void* __restrict__ Win,
                                           const void* __restrict__ bin, const int* __restrict__ fl,
                                           float* __restrict__ x){
  int isf = fl[0];
  __shared__ float Ws[FIN * HD];
  __shared__ float fs[4 * FIN];
  __shared__ float bs[HD];
  int t = threadIdx.x;
  for (int idx = t; idx < FIN * HD; idx += 256) Ws[idx] = ldin(Win, idx, isf);
  if (t < HD) bs[t] = ldin(bin, t, isf);
  int n0 = blockIdx.x * 4;
  for (int idx = t; idx < 4 * FIN; idx += 256){
    int nl = idx >> 7, k = idx & 127; int n = n0 + nl;
    fs[idx] = (n < NN) ? ldin(feat, (size_t)n * FIN + k, isf) : 0.f;
  }
  __syncthreads();
  int nl = t >> 6, o = t & 63; int n = n0 + nl;
  if (n < NN){
    float acc = bs[o];
    #pragma unroll 8
    for (int k = 0; k < FIN; ++k) acc += fs[nl * FIN + k] * Ws[k * HD + o];
    x[(size_t)n * HD + o] = fmaxf(acc, 0.f);
  }
}

__global__ __launch_bounds__(256) void k_qkv(const float* __restrict__ x,
    const void* __restrict__ WQ, const void* __restrict__ bQ,
    const void* __restrict__ WK, const void* __restrict__ bK,
    const void* __restrict__ WV, const void* __restrict__ bV,
    const void* __restrict__ hopwise, const int* __restrict__ fl,
    float* __restrict__ Q, u16* __restrict__ Kf0b, u16* __restrict__ Vb,
    float* __restrict__ hid){
  int isf = fl[0];
  __shared__ float WQs[HD * HD], WKs[HD * HD], WVs[HD * CD];
  __shared__ float bqs[HD], bks[HD], bvs[CD];
  __shared__ float xs[4 * HD];
  int t = threadIdx.x;
  for (int idx = t; idx < HD * HD; idx += 256){ WQs[idx] = ldin(WQ, idx, isf); WKs[idx] = ldin(WK, idx, isf); }
  for (int idx = t; idx < HD * CD; idx += 256) WVs[idx] = ldin(WV, idx, isf);
  if (t < HD){ bqs[t] = ldin(bQ, t, isf); bks[t] = ldin(bK, t, isf); }
  if (t < CD) bvs[t] = ldin(bV, t, isf);
  int n0 = blockIdx.x * 4;
  for (int idx = t; idx < 4 * HD; idx += 256){
    int nl = idx >> 6; int n = n0 + nl;
    xs[idx] = (n < NN) ? x[(size_t)n * HD + (idx & 63)] : 0.f;
  }
  __syncthreads();
  int nl = t >> 6, o = t & 63; int n = n0 + nl;
  float hw0 = ldin(hopwise, 0, isf);
  float q = bqs[o], kf = bks[o];
  #pragma unroll 8
  for (int k = 0; k < HD; ++k){
    float xv = xs[nl * HD + k];
    q  += xv * WQs[k * HD + o];
    kf += xv * WKs[k * HD + o];
  }
  q  = (q  > 0.f) ? 1.f + q  : expf(q);
  kf = (kf > 0.f) ? 1.f + kf : expf(kf);
  if (n < NN){ Q[(size_t)n * HD + o] = q; Kf0b[(size_t)n * HD + o] = f2b(kf); }
  if (o < CD && n < NN){
    float v = bvs[o];
    #pragma unroll 8
    for (int k = 0; k < HD; ++k) v += xs[nl * HD + k] * WVs[k * CD + o];
    Vb[(size_t)n * CD + o] = f2b(v);
    hid[(size_t)n * CD + o] = hw0 * v;
  }
}

// ---------------- teleport sums ----------------

__global__ __launch_bounds__(256) void k_tele(const u16* __restrict__ Kf0b, const u16* __restrict__ Vb,
                                              float* __restrict__ teleM, float* __restrict__ teleK){
  __shared__ float accM[HD * CD];
  __shared__ float accKs[HD];
  __shared__ float KfL[HD];
  __shared__ float VL[CD];
  int t = threadIdx.x;
  for (int idx = t; idx < HD * CD; idx += 256) accM[idx] = 0.f;
  if (t < HD) accKs[t] = 0.f;
  __syncthreads();
  for (int n = blockIdx.x; n < NN; n += gridDim.x){
    if (t < HD) KfL[t] = b2f(Kf0b[(size_t)n * HD + t]);
    else if (t < HD + CD) VL[t - HD] = b2f(Vb[(size_t)n * CD + (t - HD)]);
    __syncthreads();
    for (int idx = t; idx < HD * CD; idx += 256){
      int h = idx >> 5, c = idx & 31;
      accM[idx] += KfL[h] * VL[c];
    }
    if (t < HD) accKs[t] += KfL[t];
    __syncthreads();
  }
  for (int idx = t; idx < HD * CD; idx += 256) atomicAdd(&teleM[idx], accM[idx]);
  if (t < HD) atomicAdd(&teleK[t], accKs[t]);
}

// ---------------- hop: gather-propagate + fused readout (+optional Kf prop) ----------------
// 128-thr block = 2 waves = 2 target nodes. Lane t = row h, columns [c0, c0+C).
// M stored fp8-e4m3 (HW cvt). FIRST: rank-1 Kf0 (x) V (bf16 reads).

template<int C, bool FIRST, bool FUSEK, bool LAST>
__global__ __launch_bounds__(128)
void k_hop(const u8* __restrict__ Min, const u16* __restrict__ Kf0b, const u16* __restrict__ Vb,
           const u16* __restrict__ KfIn, u16* __restrict__ KfOut,
           const float* __restrict__ Qb, const int2* __restrict__ ew, const int* __restrict__ ptr,
           float* __restrict__ invC, const void* __restrict__ hopw, const int* __restrict__ fl,
           int hopidx, u8* __restrict__ Mout, float* __restrict__ hid, int c0){
  int wv = threadIdx.x >> 6;
  int t = threadIdx.x & 63;
  int i = blockIdx.x * 2 + wv;
  int e0 = __builtin_amdgcn_readfirstlane(ptr[i]);
  int e1 = __builtin_amdgcn_readfirstlane(ptr[i + 1]);
  float a[C];
  #pragma unroll
  for (int j = 0; j < C; ++j) a[j] = 0.f;
  float accK = 0.f;
  int e = e0;
  if constexpr (FIRST){
    for (; e + 2 <= e1; e += 2){
      int2 d0 = ew[e], d1 = ew[e+1];
      float s0 = __int_as_float(d0.y) * b2f(Kf0b[(size_t)d0.x * HD + t]);
      float s1 = __int_as_float(d1.y) * b2f(Kf0b[(size_t)d1.x * HD + t]);
      float v0[C], v1[C];
      loadB<C>(Vb + (size_t)d0.x * CD + c0, v0);
      loadB<C>(Vb + (size_t)d1.x * CD + c0, v1);
      #pragma unroll
      for (int j = 0; j < C; ++j) a[j] += s0 * v0[j] + s1 * v1[j];
      if constexpr (FUSEK) accK += s0 + s1;
    }
    for (; e < e1; ++e){
      int2 d0 = ew[e];
      float s0 = __int_as_float(d0.y) * b2f(Kf0b[(size_t)d0.x * HD + t]);
      float v0[C];
      loadB<C>(Vb + (size_t)d0.x * CD + c0, v0);
      #pragma unroll
      for (int j = 0; j < C; ++j) a[j] += s0 * v0[j];
      if constexpr (FUSEK) accK += s0;
    }
  } else {
    for (; e + 2 <= e1; e += 2){
      int2 d0 = ew[e], d1 = ew[e+1];
      float w0 = __int_as_float(d0.y), w1 = __int_as_float(d1.y);
      float m0[C], m1[C];
      loadF8<C>(Min + (size_t)d0.x * (HD * C) + t * C, m0);
      loadF8<C>(Min + (size_t)d1.x * (HD * C) + t * C, m1);
      if constexpr (FUSEK){
        accK += w0 * b2f(KfIn[(size_t)d0.x * HD + t]) + w1 * b2f(KfIn[(size_t)d1.x * HD + t]);
      }
      #pragma unroll
      for (int j = 0; j < C; ++j) a[j] += w0 * m0[j] + w1 * m1[j];
    }
    for (; e < e1; ++e){
      int2 d0 = ew[e];
      float w0 = __int_as_float(d0.y);
      float m0[C];
      loadF8<C>(Min + (size_t)d0.x * (HD * C) + t * C, m0);
      if constexpr (FUSEK) accK += w0 * b2f(KfIn[(size_t)d0.x * HD + t]);
      #pragma unroll
      for (int j = 0; j < C; ++j) a[j] += w0 * m0[j];
    }
  }
  float q = Qb[(size_t)i * HD + t];
  float ic;
  if constexpr (FUSEK){
    if constexpr (!LAST) KfOut[(size_t)i * HD + t] = f2b(accK);
    float ck = q * accK;
    #pragma unroll
    for (int off = 32; off >= 1; off >>= 1) ck += __shfl_down(ck, off, 64);
    ck = 1.f / (ck + CSTV);          // valid on lane 0
    if (t == 0) invC[i] = ck;
    ic = ck;
  } else {
    ic = invC[i];
  }
  float p[C];
  #pragma unroll
  for (int j = 0; j < C; ++j) p[j] = q * a[j];
  #pragma unroll
  for (int off = 32; off >= 1; off >>= 1){
    #pragma unroll
    for (int j = 0; j < C; ++j) p[j] += __shfl_down(p[j], off, 64);
  }
  if (t == 0){
    float coef = ldin(hopw, hopidx, fl[0]) * ic;
    float* hp = hid + (size_t)i * CD + c0;
    #pragma unroll
    for (int j = 0; j < C; ++j) hp[j] += coef * p[j];
  }
  if constexpr (!LAST) storeF8NT<C>(Mout + (size_t)i * (HD * C) + t * C, a);
}

// ---------------- teleport branch + output ----------------

__global__ __launch_bounds__(256) void k_final(const float* __restrict__ hid, const float* __restrict__ Qb,
    const float* __restrict__ teleM, const float* __restrict__ teleK, const void* __restrict__ tel,
    const int* __restrict__ fl, void* __restrict__ out){
  int isf = fl[0];
  __shared__ float tM[HD * CD];
  __shared__ float tK[HD];
  int t = threadIdx.x;
  for (int idx = t; idx < HD * CD; idx += 256) tM[idx] = teleM[idx];
  if (t < HD) tK[t] = teleK[t];
  __syncthreads();
  int nl = t >> 5, c = t & 31;
  int n = blockIdx.x * 8 + nl;
  if (n < NN){
    const float* q = Qb + (size_t)n * HD;
    float dH = 0.f, dK = 0.f;
    #pragma unroll 8
    for (int h = 0; h < HD; ++h){
      float qv = q[h];
      dH += qv * tM[h * CD + c];
      dK += qv * tK[h];
    }
    float invn = 1.f / (float)NN;
    float tH = (dH * invn) / (dK * invn + CSTV);
    float val = hid[(size_t)n * CD + c] + ldin(tel, 0, isf) * tH;
    if (isf) ((float*)out)[(size_t)n * CD + c] = val;
    else ((u16*)out)[(size_t)n * CD + c] = f2b(val);
  }
}

// ---------------- host-side hop sequencing ----------------

template<int C>
static void launch_chunks(u8* Ma, u8* Mb, const u16* Kf0b, const u16* Vb,
                          u16* KfPa, u16* KfPb, const float* Q, const int2* ew,
                          const int* ptr, float* invC, const void* hop, const int* flag,
                          float* hid, hipStream_t stream){
  int nchunks = CD / C;
  int grid = NN / 2;
  for (int ch = 0; ch < nchunks; ++ch){
    int c0 = ch * C;
    if (ch == 0){
      k_hop<C,true ,true ,false><<<grid,128,0,stream>>>(nullptr, Kf0b, Vb, nullptr, KfPa, Q, ew, ptr, invC+0*NN, hop, flag, 1, Ma, hid, c0);
      k_hop<C,false,true ,false><<<grid,128,0,stream>>>(Ma, Kf0b, Vb, KfPa, KfPb, Q, ew, ptr, invC+1*NN, hop, flag, 2, Mb, hid, c0);
      k_hop<C,false,true ,false><<<grid,128,0,stream>>>(Mb, Kf0b, Vb, KfPb, KfPa, Q, ew, ptr, invC+2*NN, hop, flag, 3, Ma, hid, c0);
      k_hop<C,false,true ,true ><<<grid,128,0,stream>>>(Ma, Kf0b, Vb, KfPa, nullptr, Q, ew, ptr, invC+3*NN, hop, flag, 4, nullptr, hid, c0);
    } else {
      k_hop<C,true ,false,false><<<grid,128,0,stream>>>(nullptr, Kf0b, Vb, nullptr, nullptr, Q, ew, ptr, invC+0*NN, hop, flag, 1, Ma, hid, c0);
      k_hop<C,false,false,false><<<grid,128,0,stream>>>(Ma, Kf0b, Vb, nullptr, nullptr, Q, ew, ptr, invC+1*NN, hop, flag, 2, Mb, hid, c0);
      k_hop<C,false,false,false><<<grid,128,0,stream>>>(Mb, Kf0b, Vb, nullptr, nullptr, Q, ew, ptr, invC+2*NN, hop, flag, 3, Ma, hid, c0);
      k_hop<C,false,false,true ><<<grid,128,0,stream>>>(Ma, Kf0b, Vb, nullptr, nullptr, Q, ew, ptr, invC+3*NN, hop, flag, 4, nullptr, hid, c0);
    }
  }
}

// ---------------- launch ----------------

extern "C" void kernel_launch(void* const* d_in, const int* in_sizes, int n_in,
                              void* d_out, int out_size, void* d_ws, size_t ws_size,
                              hipStream_t stream){
  const void* feat = d_in[0];
  const void* Win  = d_in[1];
  const void* bin  = d_in[2];
  const void* WQ   = d_in[3];
  const void* bQ   = d_in[4];
  const void* WK   = d_in[5];
  const void* bK   = d_in[6];
  const void* WV   = d_in[7];
  const void* bV   = d_in[8];
  const void* hop  = d_in[9];
  const void* tel  = d_in[10];
  const int* ei    = (const int*)d_in[11];
  const int* rowp  = ei;
  const int* colp  = ei + EE;

  char* w = (char*)d_ws;
  size_t off = 0;
  auto pad = [](size_t x){ return (x + 255) & ~((size_t)255); };
  auto alloc = [&](size_t bytes) -> char* {
    char* p = w + off;
    off += pad(bytes);
    return p;
  };
  float* Q    = (float*)alloc((size_t)NN * HD * 4);
  float* hid  = (float*)alloc((size_t)NN * CD * 4);
  float* invC = (float*)alloc((size_t)4 * NN * 4);
  float* dinv = (float*)alloc((size_t)NN * 4);
  int*   cnt  = (int*)alloc((size_t)NN * 4);
  int*   ptr  = (int*)alloc((size_t)(NN + 1) * 4);
  int*   fill = (int*)alloc((size_t)NN * 4);
  int*   bsum = (int*)alloc(64 * 4);
  int*   boff = (int*)alloc(64 * 4);
  int2*  ew   = (int2*)alloc((size_t)EE * 8);
  float* teleM= (float*)alloc((size_t)HD * CD * 4);
  float* teleK= (float*)alloc((size_t)HD * 4);
  int*   flag = (int*)alloc(256);
  u16*   Kf0b = (u16*)alloc((size_t)NN * HD * 2);
  u16*   KfPa = (u16*)alloc((size_t)NN * HD * 2);
  u16*   KfPb = (u16*)alloc((size_t)NN * HD * 2);
  u16*   Vb   = (u16*)alloc((size_t)NN * CD * 2);

  size_t fixed = off;
  auto fits = [&](int C){ return fixed + 2 * pad((size_t)NN * HD * C) <= ws_size; };
  int C = fits(32) ? 32 : (fits(16) ? 16 : 8);
  size_t mbytes = pad((size_t)NN * HD * C);
  char* mreg = alloc(2 * mbytes);
  u8* Ma = (u8*)mreg;
  u8* Mb = (u8*)(mreg + mbytes);
  float* x = (float*)mreg;  // x (12.8 MB) aliases M region (>=25 MB in all tiers); dead before hops

  k_detect<<<1, 256, 0, stream>>>((const u16*)Win, flag);
  k_zero<<<(NN + 255) / 256, 256, 0, stream>>>(cnt, teleM, teleK);
  k_hist<<<(EE + 255) / 256, 256, 0, stream>>>(colp, cnt);
  k_scanA<<<NB, 1024, 0, stream>>>(cnt, fill, bsum);
  k_scanB<<<1, 64, 0, stream>>>(bsum, boff, ptr + NN);
  k_scanC<<<NB, 1024, 0, stream>>>(cnt, fill, boff, ptr, fill, dinv);
  k_scatter<<<(EE + 255) / 256, 256, 0, stream>>>(rowp, colp, dinv, fill, ew);
  k_x<<<(NN + 3) / 4, 256, 0, stream>>>(feat, Win, bin, flag, x);
  k_qkv<<<(NN + 3) / 4, 256, 0, stream>>>(x, WQ, bQ, WK, bK, WV, bV, hop, flag, Q, Kf0b, Vb, hid);
  k_tele<<<256, 256, 0, stream>>>(Kf0b, Vb, teleM, teleK);

  if (C == 32)      launch_chunks<32>(Ma, Mb, Kf0b, Vb, KfPa, KfPb, Q, ew, ptr, invC, hop, flag, hid, stream);
  else if (C == 16) launch_chunks<16>(Ma, Mb, Kf0b, Vb, KfPa, KfPb, Q, ew, ptr, invC, hop, flag, hid, stream);
  else              launch_chunks<8 >(Ma, Mb, Kf0b, Vb, KfPa, KfPb, Q, ew, ptr, invC, hop, flag, hid, stream);

  k_final<<<(NN + 7) / 8, 256, 0, stream>>>(hid, Q, teleM, teleK, tel, flag, d_out);
}

// Round 8
// 2106.290 us; speedup vs baseline: 1.7511x; 1.0819x over previous
//
#include <hip/hip_runtime.h>
#include <math.h>
#include <stdint.h>

#define NN 50000
#define FIN 128
#define HD 64
#define CD 32
#define EE 1600000
#define CSTV 1e-5f
#define NB 49  // ceil(NN/1024)

typedef unsigned short u16;
typedef unsigned int u32;
typedef unsigned char u8;
typedef unsigned int uv2 __attribute__((ext_vector_type(2)));
typedef unsigned int uv4 __attribute__((ext_vector_type(4)));
typedef float fv2 __attribute__((ext_vector_type(2)));

static __device__ __forceinline__ float b2f(u16 u){
  union { float f; u32 i; } v; v.i = ((u32)u) << 16; return v.f;
}
static __device__ __forceinline__ u16 f2b(float f){
  union { float f; u32 u; } v; v.f = f;
  u32 u = v.u;
  u32 r = (u + 0x7fffu + ((u >> 16) & 1u)) >> 16;
  return (u16)r;
}
static __device__ __forceinline__ float ldin(const void* p, size_t i, int isf){
  return isf ? ((const float*)p)[i] : b2f(((const u16*)p)[i]);
}

// ---- fp8 e4m3 via HW converters (encode/decode matched => self-consistent) ----
static __device__ __forceinline__ void dec8(u32 g, float* f){
  fv2 lo = __builtin_amdgcn_cvt_pk_f32_fp8(g, false);
  fv2 hi = __builtin_amdgcn_cvt_pk_f32_fp8(g, true);
  f[0] = lo.x; f[1] = lo.y; f[2] = hi.x; f[3] = hi.y;
}
static __device__ __forceinline__ u32 enc8(const float* f){
  u32 r = 0;
  r = __builtin_amdgcn_cvt_pk_fp8_f32(f[0], f[1], r, false);
  r = __builtin_amdgcn_cvt_pk_fp8_f32(f[2], f[3], r, true);
  return r;
}
template<int C>
static __device__ __forceinline__ void loadF8(const u8* __restrict__ p, float* f){
  if constexpr (C == 32){
    uint4 g0 = ((const uint4*)p)[0];
    uint4 g1 = ((const uint4*)p)[1];
    dec8(g0.x, f+0);  dec8(g0.y, f+4);  dec8(g0.z, f+8);  dec8(g0.w, f+12);
    dec8(g1.x, f+16); dec8(g1.y, f+20); dec8(g1.z, f+24); dec8(g1.w, f+28);
  } else if constexpr (C == 16){
    uint4 g = *(const uint4*)p;
    dec8(g.x, f+0); dec8(g.y, f+4); dec8(g.z, f+8); dec8(g.w, f+12);
  } else {
    uint2 g = *(const uint2*)p;
    dec8(g.x, f+0); dec8(g.y, f+4);
  }
}
template<int C>
static __device__ __forceinline__ void storeF8NT(u8* __restrict__ p, const float* f){
  if constexpr (C == 32){
    uv4 g0, g1;
    g0.x=enc8(f+0);  g0.y=enc8(f+4);  g0.z=enc8(f+8);  g0.w=enc8(f+12);
    g1.x=enc8(f+16); g1.y=enc8(f+20); g1.z=enc8(f+24); g1.w=enc8(f+28);
    __builtin_nontemporal_store(g0, (uv4*)p);
    __builtin_nontemporal_store(g1, (uv4*)p + 1);
  } else if constexpr (C == 16){
    uv4 g; g.x=enc8(f+0); g.y=enc8(f+4); g.z=enc8(f+8); g.w=enc8(f+12);
    __builtin_nontemporal_store(g, (uv4*)p);
  } else {
    uv2 g; g.x=enc8(f+0); g.y=enc8(f+4);
    __builtin_nontemporal_store(g, (uv2*)p);
  }
}

// ---------------- zero + dtype detect ----------------
__global__ void k_zero(const u16* __restrict__ w, int* __restrict__ flag,
                       int* cnt, float* teleM, float* teleK){
  int i = blockIdx.x * 256 + threadIdx.x;
  if (i < NN) cnt[i] = 0;
  if (i < HD * CD) teleM[i] = 0.f;
  if (i < HD) teleK[i] = 0.f;
  if (blockIdx.x == 0){
    __shared__ int bad;
    if (threadIdx.x == 0) bad = 0;
    __syncthreads();
    for (int k = threadIdx.x; k < 2048; k += 256){
      float v = b2f(w[k]);
      if (!(fabsf(v) <= 1.0f)) bad = 1;   // fp32 halves look huge/NaN as bf16
    }
    __syncthreads();
    if (threadIdx.x == 0) flag[0] = bad;  // 1 = fp32 inputs, 0 = bf16
  }
}

// ---------------- CSR build ----------------

__global__ void k_hist(const int* __restrict__ colp, int* __restrict__ cnt){
  int e = blockIdx.x * 256 + threadIdx.x;
  if (e < EE) atomicAdd(&cnt[colp[e]], 1);
}

__global__ __launch_bounds__(1024) void k_scanA(const int* __restrict__ cnt,
                                                int* __restrict__ loc, int* __restrict__ bsum){
  __shared__ int wsum[16];
  int t = threadIdx.x; int i = blockIdx.x * 1024 + t;
  int v = (i < NN) ? cnt[i] : 0;
  int x = v;
  int lane = t & 63, wid = t >> 6;
  #pragma unroll
  for (int d = 1; d < 64; d <<= 1){ int n = __shfl_up(x, d, 64); if (lane >= d) x += n; }
  if (lane == 63) wsum[wid] = x;
  __syncthreads();
  if (t < 16){
    int y = wsum[t];
    #pragma unroll
    for (int d = 1; d < 16; d <<= 1){ int n = __shfl_up(y, d, 16); if (t >= d) y += n; }
    wsum[t] = y;
  }
  __syncthreads();
  if (wid > 0) x += wsum[wid - 1];
  if (i < NN) loc[i] = x;
  if (t == 1023) bsum[blockIdx.x] = x;
}

__global__ __launch_bounds__(64) void k_scanB(const int* __restrict__ bsum,
                                              int* __restrict__ boff, int* __restrict__ ptrNN){
  int t = threadIdx.x;
  int v = (t < NB) ? bsum[t] : 0;
  int x = v;
  #pragma unroll
  for (int d = 1; d < 64; d <<= 1){ int n = __shfl_up(x, d, 64); if (t >= d) x += n; }
  if (t < NB) boff[t] = x - v;
  if (t == 63) ptrNN[0] = x;
}

__global__ __launch_bounds__(1024) void k_scanC(const int* __restrict__ cnt, const int* __restrict__ loc,
                                                const int* __restrict__ boff, int* __restrict__ ptr,
                                                int* __restrict__ fill, float* __restrict__ dinv){
  int i = blockIdx.x * 1024 + threadIdx.x;
  if (i < NN){
    int c = cnt[i];
    int p = boff[blockIdx.x] + loc[i] - c;
    ptr[i] = p; fill[i] = p;
    dinv[i] = (c > 0) ? 1.f / (float)c : 0.f;
  }
}

__global__ void k_scatter(const int* __restrict__ rowp, const int* __restrict__ colp,
                          const float* __restrict__ dinv, int* __restrict__ fill,
                          int2* __restrict__ ew){
  int e = blockIdx.x * 256 + threadIdx.x;
  if (e < EE){
    int c = colp[e];
    int p = atomicAdd(&fill[c], 1);
    int r = rowp[e];
    int2 v; v.x = r; v.y = __float_as_int(dinv[r]);
    ew[p] = v;
  }
}

// ---------------- fused featurizer: x -> Q,Kf,V (8 nodes/block) ----------------
// Weights staged in LDS as bf16 (43 KB total -> 3 blocks/CU), fp32 accumulate.

__global__ __launch_bounds__(256) void k_feat(
    const void* __restrict__ feat, const void* __restrict__ Win, const void* __restrict__ bin,
    const void* __restrict__ WQ, const void* __restrict__ bQ,
    const void* __restrict__ WK, const void* __restrict__ bK,
    const void* __restrict__ WV, const void* __restrict__ bV,
    const void* __restrict__ hopwise, const int* __restrict__ fl,
    float* __restrict__ Q, u16* __restrict__ Kf0b, float* __restrict__ V32,
    float* __restrict__ hid){
  int isf = fl[0];
  __shared__ u16 Ws[FIN * HD];        // 16 KB
  __shared__ u16 WQs[HD * HD];        // 8 KB
  __shared__ u16 WKs[HD * HD];        // 8 KB
  __shared__ u16 WVs[HD * CD];        // 4 KB
  __shared__ float bs[HD], bqs[HD], bks[HD], bvs[CD];
  __shared__ float fs[8 * FIN];       // 4 KB
  __shared__ float xs[8 * HD];        // 2 KB
  int t = threadIdx.x;
  for (int idx = t; idx < FIN * HD; idx += 256) Ws[idx] = f2b(ldin(Win, idx, isf));
  for (int idx = t; idx < HD * HD; idx += 256){
    WQs[idx] = f2b(ldin(WQ, idx, isf));
    WKs[idx] = f2b(ldin(WK, idx, isf));
  }
  for (int idx = t; idx < HD * CD; idx += 256) WVs[idx] = f2b(ldin(WV, idx, isf));
  if (t < HD){ bs[t] = ldin(bin, t, isf); bqs[t] = ldin(bQ, t, isf); bks[t] = ldin(bK, t, isf); }
  if (t < CD) bvs[t] = ldin(bV, t, isf);
  int n0 = blockIdx.x * 8;
  for (int idx = t; idx < 8 * FIN; idx += 256){
    int nl = idx >> 7, k = idx & 127; int n = n0 + nl;
    fs[idx] = (n < NN) ? ldin(feat, (size_t)n * FIN + k, isf) : 0.f;
  }
  __syncthreads();
  // x = relu(feat @ Win + bin): 512 outputs, 2 per thread
  int o = t & 63, g = t >> 6;
  #pragma unroll
  for (int rep = 0; rep < 2; ++rep){
    int nl = g + rep * 4;
    float acc = bs[o];
    #pragma unroll 8
    for (int k = 0; k < FIN; ++k) acc += fs[nl * FIN + k] * b2f(Ws[k * HD + o]);
    xs[nl * HD + o] = fmaxf(acc, 0.f);
  }
  __syncthreads();
  float hw0 = ldin(hopwise, 0, isf);
  #pragma unroll
  for (int rep = 0; rep < 2; ++rep){
    int nl = g + rep * 4; int n = n0 + nl;
    float q = bqs[o], kf = bks[o];
    #pragma unroll 8
    for (int k = 0; k < HD; ++k){
      float xv = xs[nl * HD + k];
      q  += xv * b2f(WQs[k * HD + o]);
      kf += xv * b2f(WKs[k * HD + o]);
    }
    q  = (q  > 0.f) ? 1.f + q  : expf(q);
    kf = (kf > 0.f) ? 1.f + kf : expf(kf);
    if (n < NN){ Q[(size_t)n * HD + o] = q; Kf0b[(size_t)n * HD + o] = f2b(kf); }
  }
  // V: 256 outputs, 1 per thread
  int nv = t >> 5, c = t & 31; int n = n0 + nv;
  if (n < NN){
    float v = bvs[c];
    #pragma unroll 8
    for (int k = 0; k < HD; ++k) v += xs[nv * HD + k] * b2f(WVs[k * CD + c]);
    V32[(size_t)n * CD + c] = v;
    hid[(size_t)n * CD + c] = hw0 * v;
  }
}

// ---------------- teleport sums ----------------

__global__ __launch_bounds__(256) void k_tele(const u16* __restrict__ Kf0b, const float* __restrict__ V32,
                                              float* __restrict__ teleM, float* __restrict__ teleK){
  __shared__ float accM[HD * CD];
  __shared__ float accKs[HD];
  __shared__ float KfL[HD];
  __shared__ float VL[CD];
  int t = threadIdx.x;
  for (int idx = t; idx < HD * CD; idx += 256) accM[idx] = 0.f;
  if (t < HD) accKs[t] = 0.f;
  __syncthreads();
  for (int n = blockIdx.x; n < NN; n += gridDim.x){
    if (t < HD) KfL[t] = b2f(Kf0b[(size_t)n * HD + t]);
    else if (t < HD + CD) VL[t - HD] = V32[(size_t)n * CD + (t - HD)];
    __syncthreads();
    for (int idx = t; idx < HD * CD; idx += 256){
      int h = idx >> 5, c = idx & 31;
      accM[idx] += KfL[h] * VL[c];
    }
    if (t < HD) accKs[t] += KfL[t];
    __syncthreads();
  }
  for (int idx = t; idx < HD * CD; idx += 256) atomicAdd(&teleM[idx], accM[idx]);
  if (t < HD) atomicAdd(&teleK[t], accKs[t]);
}

// ---------------- hop: gather-propagate + fused readout (+optional Kf prop) ----------------
// 128-thr block = 2 waves = 2 target nodes. Lane t = row h, columns [c0, c0+C).
// M stored fp8-e4m3. FIRST: rank-1 Kf0 (x) V, V via uniform fp32 loads (scalar path).

template<int C, bool FIRST, bool FUSEK, bool LAST>
__global__ __launch_bounds__(128)
void k_hop(const u8* __restrict__ Min, const u16* __restrict__ Kf0b, const float* __restrict__ V32,
           const u16* __restrict__ KfIn, u16* __restrict__ KfOut,
           const float* __restrict__ Qb, const int2* __restrict__ ew, const int* __restrict__ ptr,
           float* __restrict__ invC, const void* __restrict__ hopw, const int* __restrict__ fl,
           int hopidx, u8* __restrict__ Mout, float* __restrict__ hid, int c0){
  int wv = threadIdx.x >> 6;
  int t = threadIdx.x & 63;
  int i = blockIdx.x * 2 + wv;
  int e0 = __builtin_amdgcn_readfirstlane(ptr[i]);
  int e1 = __builtin_amdgcn_readfirstlane(ptr[i + 1]);
  float a[C];
  #pragma unroll
  for (int j = 0; j < C; ++j) a[j] = 0.f;
  float accK = 0.f;
  int e = e0;
  if constexpr (FIRST){
    for (; e + 2 <= e1; e += 2){
      int2 d0 = ew[e], d1 = ew[e+1];
      int r0 = __builtin_amdgcn_readfirstlane(d0.x);
      int r1 = __builtin_amdgcn_readfirstlane(d1.x);
      float w0 = __int_as_float(__builtin_amdgcn_readfirstlane(d0.y));
      float w1 = __int_as_float(__builtin_amdgcn_readfirstlane(d1.y));
      float s0 = w0 * b2f(Kf0b[(size_t)r0 * HD + t]);
      float s1 = w1 * b2f(Kf0b[(size_t)r1 * HD + t]);
      const float* vp0 = V32 + (size_t)r0 * CD + c0;
      const float* vp1 = V32 + (size_t)r1 * CD + c0;
      #pragma unroll
      for (int j = 0; j < C; ++j) a[j] += s0 * vp0[j] + s1 * vp1[j];
      if constexpr (FUSEK) accK += s0 + s1;
    }
    for (; e < e1; ++e){
      int2 d0 = ew[e];
      int r0 = __builtin_amdgcn_readfirstlane(d0.x);
      float w0 = __int_as_float(__builtin_amdgcn_readfirstlane(d0.y));
      float s0 = w0 * b2f(Kf0b[(size_t)r0 * HD + t]);
      const float* vp0 = V32 + (size_t)r0 * CD + c0;
      #pragma unroll
      for (int j = 0; j < C; ++j) a[j] += s0 * vp0[j];
      if constexpr (FUSEK) accK += s0;
    }
  } else {
    for (; e + 2 <= e1; e += 2){
      int2 d0 = ew[e], d1 = ew[e+1];
      float w0 = __int_as_float(d0.y), w1 = __int_as_float(d1.y);
      float m0[C], m1[C];
      loadF8<C>(Min + (size_t)d0.x * (HD * C) + t * C, m0);
      loadF8<C>(Min + (size_t)d1.x * (HD * C) + t * C, m1);
      if constexpr (FUSEK){
        accK += w0 * b2f(KfIn[(size_t)d0.x * HD + t]) + w1 * b2f(KfIn[(size_t)d1.x * HD + t]);
      }
      #pragma unroll
      for (int j = 0; j < C; ++j) a[j] += w0 * m0[j] + w1 * m1[j];
    }
    for (; e < e1; ++e){
      int2 d0 = ew[e];
      float w0 = __int_as_float(d0.y);
      float m0[C];
      loadF8<C>(Min + (size_t)d0.x * (HD * C) + t * C, m0);
      if constexpr (FUSEK) accK += w0 * b2f(KfIn[(size_t)d0.x * HD + t]);
      #pragma unroll
      for (int j = 0; j < C; ++j) a[j] += w0 * m0[j];
    }
  }
  float q = Qb[(size_t)i * HD + t];
  float ic;
  if constexpr (FUSEK){
    if constexpr (!LAST) KfOut[(size_t)i * HD + t] = f2b(accK);
    float ck = q * accK;
    #pragma unroll
    for (int off = 32; off >= 1; off >>= 1) ck += __shfl_down(ck, off, 64);
    ck = 1.f / (ck + CSTV);          // valid on lane 0
    if (t == 0) invC[i] = ck;
    ic = ck;
  } else {
    ic = invC[i];
  }
  float p[C];
  #pragma unroll
  for (int j = 0; j < C; ++j) p[j] = q * a[j];
  #pragma unroll
  for (int off = 32; off >= 1; off >>= 1){
    #pragma unroll
    for (int j = 0; j < C; ++j) p[j] += __shfl_down(p[j], off, 64);
  }
  if (t == 0){
    float coef = ldin(hopw, hopidx, fl[0]) * ic;
    float* hp = hid + (size_t)i * CD + c0;
    #pragma unroll
    for (int j = 0; j < C; ++j) hp[j] += coef * p[j];
  }
  if constexpr (!LAST) storeF8NT<C>(Mout + (size_t)i * (HD * C) + t * C, a);
}

// ---------------- teleport branch + output ----------------

__global__ __launch_bounds__(256) void k_final(const float* __restrict__ hid, const float* __restrict__ Qb,
    const float* __restrict__ teleM, const float* __restrict__ teleK, const void* __restrict__ tel,
    const int* __restrict__ fl, void* __restrict__ out){
  int isf = fl[0];
  __shared__ float tM[HD * CD];
  __shared__ float tK[HD];
  int t = threadIdx.x;
  for (int idx = t; idx < HD * CD; idx += 256) tM[idx] = teleM[idx];
  if (t < HD) tK[t] = teleK[t];
  __syncthreads();
  int nl = t >> 5, c = t & 31;
  int n = blockIdx.x * 8 + nl;
  if (n < NN){
    const float* q = Qb + (size_t)n * HD;
    float dH = 0.f, dK = 0.f;
    #pragma unroll 8
    for (int h = 0; h < HD; ++h){
      float qv = q[h];
      dH += qv * tM[h * CD + c];
      dK += qv * tK[h];
    }
    float invn = 1.f / (float)NN;
    float tH = (dH * invn) / (dK * invn + CSTV);
    float val = hid[(size_t)n * CD + c] + ldin(tel, 0, isf) * tH;
    if (isf) ((float*)out)[(size_t)n * CD + c] = val;
    else ((u16*)out)[(size_t)n * CD + c] = f2b(val);
  }
}

// ---------------- host-side hop sequencing ----------------

template<int C>
static void launch_chunks(u8* Ma, u8* Mb, const u16* Kf0b, const float* V32,
                          u16* KfPa, u16* KfPb, const float* Q, const int2* ew,
                          const int* ptr, float* invC, const void* hop, const int* flag,
                          float* hid, hipStream_t stream){
  int nchunks = CD / C;
  int grid = NN / 2;
  for (int ch = 0; ch < nchunks; ++ch){
    int c0 = ch * C;
    if (ch == 0){
      k_hop<C,true ,true ,false><<<grid,128,0,stream>>>(nullptr, Kf0b, V32, nullptr, KfPa, Q, ew, ptr, invC+0*NN, hop, flag, 1, Ma, hid, c0);
      k_hop<C,false,true ,false><<<grid,128,0,stream>>>(Ma, Kf0b, V32, KfPa, KfPb, Q, ew, ptr, invC+1*NN, hop, flag, 2, Mb, hid, c0);
      k_hop<C,false,true ,false><<<grid,128,0,stream>>>(Mb, Kf0b, V32, KfPb, KfPa, Q, ew, ptr, invC+2*NN, hop, flag, 3, Ma, hid, c0);
      k_hop<C,false,true ,true ><<<grid,128,0,stream>>>(Ma, Kf0b, V32, KfPa, nullptr, Q, ew, ptr, invC+3*NN, hop, flag, 4, nullptr, hid, c0);
    } else {
      k_hop<C,true ,false,false><<<grid,128,0,stream>>>(nullptr, Kf0b, V32, nullptr, nullptr, Q, ew, ptr, invC+0*NN, hop, flag, 1, Ma, hid, c0);
      k_hop<C,false,false,false><<<grid,128,0,stream>>>(Ma, Kf0b, V32, nullptr, nullptr, Q, ew, ptr, invC+1*NN, hop, flag, 2, Mb, hid, c0);
      k_hop<C,false,false,false><<<grid,128,0,stream>>>(Mb, Kf0b, V32, nullptr, nullptr, Q, ew, ptr, invC+2*NN, hop, flag, 3, Ma, hid, c0);
      k_hop<C,false,false,true ><<<grid,128,0,stream>>>(Ma, Kf0b, V32, nullptr, nullptr, Q, ew, ptr, invC+3*NN, hop, flag, 4, nullptr, hid, c0);
    }
  }
}

// ---------------- launch ----------------

extern "C" void kernel_launch(void* const* d_in, const int* in_sizes, int n_in,
                              void* d_out, int out_size, void* d_ws, size_t ws_size,
                              hipStream_t stream){
  const void* feat = d_in[0];
  const void* Win  = d_in[1];
  const void* bin  = d_in[2];
  const void* WQ   = d_in[3];
  const void* bQ   = d_in[4];
  const void* WK   = d_in[5];
  const void* bK   = d_in[6];
  const void* WV   = d_in[7];
  const void* bV   = d_in[8];
  const void* hop  = d_in[9];
  const void* tel  = d_in[10];
  const int* ei    = (const int*)d_in[11];
  const int* rowp  = ei;
  const int* colp  = ei + EE;

  char* w = (char*)d_ws;
  size_t off = 0;
  auto pad = [](size_t x){ return (x + 255) & ~((size_t)255); };
  auto alloc = [&](size_t bytes) -> char* {
    char* p = w + off;
    off += pad(bytes);
    return p;
  };
  float* Q    = (float*)alloc((size_t)NN * HD * 4);
  float* hid  = (float*)alloc((size_t)NN * CD * 4);
  float* invC = (float*)alloc((size_t)4 * NN * 4);
  float* dinv = (float*)alloc((size_t)NN * 4);
  int*   cnt  = (int*)alloc((size_t)NN * 4);
  int*   ptr  = (int*)alloc((size_t)(NN + 1) * 4);
  int*   fill = (int*)alloc((size_t)NN * 4);
  int*   bsum = (int*)alloc(64 * 4);
  int*   boff = (int*)alloc(64 * 4);
  int2*  ew   = (int2*)alloc((size_t)EE * 8);
  float* teleM= (float*)alloc((size_t)HD * CD * 4);
  float* teleK= (float*)alloc((size_t)HD * 4);
  int*   flag = (int*)alloc(256);
  u16*   Kf0b = (u16*)alloc((size_t)NN * HD * 2);
  u16*   KfPa = (u16*)alloc((size_t)NN * HD * 2);
  u16*   KfPb = (u16*)alloc((size_t)NN * HD * 2);
  float* V32  = (float*)alloc((size_t)NN * CD * 4);

  size_t fixed = off;
  auto fits = [&](int C){ return fixed + 2 * pad((size_t)NN * HD * C) <= ws_size; };
  int C = fits(32) ? 32 : (fits(16) ? 16 : 8);
  size_t mbytes = pad((size_t)NN * HD * C);
  char* mreg = alloc(2 * mbytes);
  u8* Ma = (u8*)mreg;
  u8* Mb = (u8*)(mreg + mbytes);

  k_zero<<<(NN + 255) / 256, 256, 0, stream>>>((const u16*)Win, flag, cnt, teleM, teleK);
  k_hist<<<(EE + 255) / 256, 256, 0, stream>>>(colp, cnt);
  k_scanA<<<NB, 1024, 0, stream>>>(cnt, fill, bsum);
  k_scanB<<<1, 64, 0, stream>>>(bsum, boff, ptr + NN);
  k_scanC<<<NB, 1024, 0, stream>>>(cnt, fill, boff, ptr, fill, dinv);
  k_scatter<<<(EE + 255) / 256, 256, 0, stream>>>(rowp, colp, dinv, fill, ew);
  k_feat<<<(NN + 7) / 8, 256, 0, stream>>>(feat, Win, bin, WQ, bQ, WK, bK, WV, bV,
                                           hop, flag, Q, Kf0b, V32, hid);
  k_tele<<<1024, 256, 0, stream>>>(Kf0b, V32, teleM, teleK);

  if (C == 32)      launch_chunks<32>(Ma, Mb, Kf0b, V32, KfPa, KfPb, Q, ew, ptr, invC, hop, flag, hid, stream);
  else if (C == 16) launch_chunks<16>(Ma, Mb, Kf0b, V32, KfPa, KfPb, Q, ew, ptr, invC, hop, flag, hid, stream);
  else              launch_chunks<8 >(Ma, Mb, Kf0b, V32, KfPa, KfPb, Q, ew, ptr, invC, hop, flag, hid, stream);

  k_final<<<(NN + 7) / 8, 256, 0, stream>>>(hid, Q, teleM, teleK, tel, flag, d_out);
}